// Round 2
// 810.283 us; speedup vs baseline: 1.2028x; 1.2028x over previous
//
#include <hip/hip_runtime.h>
#include <hip/hip_bf16.h>
#include <cstdint>
#include <cstddef>

#define NB 1024
#define DM 512
#define NH 8
#define HD 64
#define NT 81
#define O3 1536
#define NP 96

typedef __bf16 bf16x8 __attribute__((ext_vector_type(8)));
typedef float  f32x4  __attribute__((ext_vector_type(4)));
typedef unsigned short us8 __attribute__((ext_vector_type(8)));

__device__ __forceinline__ unsigned short f2bf(float f) {
    unsigned u = __builtin_bit_cast(unsigned, f);
    u += 0x7fffu + ((u >> 16) & 1u);          // round-to-nearest-even
    return (unsigned short)(u >> 16);
}
__device__ __forceinline__ float bf2f(unsigned short h) {
    unsigned u = ((unsigned)h) << 16;
    return __builtin_bit_cast(float, u);
}
__device__ __forceinline__ bf16x8 ld8(const unsigned short* p) {
    return __builtin_bit_cast(bf16x8, *(const us8*)p);
}
__device__ __forceinline__ void async16(void* lds, const void* g) {
    __builtin_amdgcn_global_load_lds(
        (const __attribute__((address_space(1))) void*)g,
        (__attribute__((address_space(3))) void*)lds, 16, 0, 0);
}

// ---------------- kernel 1: qkv_w fp32 -> bf16 ----------------
__global__ void conv_w(const float* __restrict__ w, unsigned short* __restrict__ wb, int n) {
    int i = blockIdx.x * 256 + threadIdx.x;
    if (i < n) wb[i] = f2bf(w[i]);
}

// ---------------- kernel 1b: x fp32 [b][c][n] -> xT bf16 [b][n=96][c=512] ----------------
__global__ __launch_bounds__(256) void transpose_x(
    const float* __restrict__ x, unsigned short* __restrict__ xT)
{
    __shared__ float sT[64][85];   // stride 85: 2-way (free) banks both phases
    const int tid = threadIdx.x;
    const int b  = blockIdx.x >> 3;
    const int c0 = (blockIdx.x & 7) * 64;
    const float* xb = x + ((size_t)b * DM + c0) * NT;

    const int nn = tid & 31, cc0 = tid >> 5;
    for (int i = 0; i < 8; ++i) {
        int cc = cc0 + i * 8;
        const float* xr = xb + (size_t)cc * NT;
        #pragma unroll
        for (int j = 0; j < 3; ++j) {
            int n = nn + 32 * j;
            if (n < NT) sT[cc][n] = xr[n];
        }
    }
    __syncthreads();

    const int ci = tid & 7, n0 = tid >> 3;    // ci: c-octet, n0: 0..31
    for (int i = 0; i < 3; ++i) {
        int n = n0 + 32 * i;                  // 0..95 (pad rows -> zeros)
        us8 v;
        #pragma unroll
        for (int j = 0; j < 8; ++j) {
            float f = (n < NT) ? sT[ci * 8 + j][n] : 0.f;
            v[j] = f2bf(f);
        }
        *(us8*)(xT + ((size_t)b * NP + n) * DM + c0 + ci * 8) = v;
    }
}

// ---------------- kernel 2a: QKV GEMM, pure global_load_lds staging ----------------
#define OT 256
#define KC 32

__global__ __launch_bounds__(256) void qkv_gemm_a(
    const unsigned short* __restrict__ xT,
    const unsigned short* __restrict__ wb,
    const float* __restrict__ bias,
    const float* __restrict__ relh,
    const float* __restrict__ relw,
    unsigned short* __restrict__ qkv)
{
    __shared__ __align__(16) unsigned short sW[OT * KC];   // 16 KB, row-major [256][32]
    __shared__ __align__(16) unsigned short sX[NP * KC];   // 6 KB,  row-major [96][32]

    const int tid  = threadIdx.x;
    const int lane = tid & 63;
    const int wv   = tid >> 6;
    const int b    = blockIdx.x / 6;
    const int ot   = blockIdx.x % 6;
    const int o0   = ot * OT;
    const int r16  = lane & 15;
    const int q8   = (lane >> 4) * 8;

    f32x4 acc[4][6];
    #pragma unroll
    for (int i = 0; i < 4; ++i)
        #pragma unroll
        for (int j = 0; j < 6; ++j)
            acc[i][j] = (f32x4){0.f, 0.f, 0.f, 0.f};

    const unsigned short* xb = xT + (size_t)b * NP * DM;

    for (int kc = 0; kc < DM; kc += KC) {
        #pragma unroll
        for (int i = 0; i < 4; ++i) {
            int ch  = i * 256 + wv * 64 + lane;
            int row = ch >> 2, cb = ch & 3;
            async16(&sW[(i * 256 + wv * 64) * 8],
                    wb + (size_t)(o0 + row) * DM + kc + cb * 8);
        }
        {
            int ch  = wv * 64 + lane;
            int row = ch >> 2, cb = ch & 3;
            async16(&sX[(wv * 64) * 8], xb + (size_t)row * DM + kc + cb * 8);
            if (wv < 2) {
                int ch2  = 256 + wv * 64 + lane;
                int row2 = ch2 >> 2, cb2 = ch2 & 3;
                async16(&sX[(256 + wv * 64) * 8], xb + (size_t)row2 * DM + kc + cb2 * 8);
            }
        }
        __syncthreads();
        bf16x8 af[4], bfr[6];
        #pragma unroll
        for (int i = 0; i < 4; ++i)
            af[i] = ld8(&sW[(wv * 64 + i * 16 + r16) * KC + q8]);
        #pragma unroll
        for (int nt = 0; nt < 6; ++nt)
            bfr[nt] = ld8(&sX[(nt * 16 + r16) * KC + q8]);
        #pragma unroll
        for (int i = 0; i < 4; ++i)
            #pragma unroll
            for (int nt = 0; nt < 6; ++nt)
                acc[i][nt] = __builtin_amdgcn_mfma_f32_16x16x32_bf16(af[i], bfr[nt], acc[i][nt], 0, 0, 0);
        __syncthreads();
    }

    unsigned short* qb = qkv + (size_t)b * O3 * NT;
    #pragma unroll
    for (int i = 0; i < 4; ++i) {
        int obase = o0 + (wv * 4 + i) * 16 + (lane >> 4) * 4;   // C/D row = quad*4+reg
        #pragma unroll
        for (int nt = 0; nt < 6; ++nt) {
            int n = nt * 16 + r16;                               // C/D col
            if (n < NT) {
                #pragma unroll
                for (int r = 0; r < 4; ++r) {
                    int o = obase + r;
                    float v = acc[i][nt][r] + bias[o];
                    if (o >= DM && o < 2 * DM) {                 // K section: fold rel
                        int oo = o - DM;
                        v += relh[oo * 9 + (n % 9)] + relw[oo * 9 + (n / 9)];
                    }
                    qb[(size_t)o * NT + n] = f2bf(v);
                }
            }
        }
    }
}

// ---------------- kernel 2b: fallback GEMM (round-1 verbatim, proven) ----------------
#define OTILE 128
#define SWS 40
#define SXS 40

__global__ __launch_bounds__(256) void qkv_gemm_fb(
    const float* __restrict__ x,
    const unsigned short* __restrict__ wb,
    const float* __restrict__ bias,
    const float* __restrict__ relh,
    const float* __restrict__ relw,
    unsigned short* __restrict__ qkv)
{
    __shared__ unsigned short sW[OTILE * SWS];
    __shared__ unsigned short sXT[NP * SXS];

    const int tid  = threadIdx.x;
    const int lane = tid & 63;
    const int wv   = tid >> 6;
    const int b    = blockIdx.x / (O3 / OTILE);
    const int ot   = blockIdx.x % (O3 / OTILE);
    const int o0   = ot * OTILE;
    const int r16 = lane & 15;
    const int q8  = (lane >> 4) * 8;

    f32x4 acc[2][6];
    for (int i = 0; i < 2; ++i)
        for (int j = 0; j < 6; ++j)
            acc[i][j] = (f32x4){0.f, 0.f, 0.f, 0.f};

    const float* xb = x + (size_t)b * DM * NT;
    const int wr  = tid >> 2;
    const int wc  = (tid & 3) * 8;
    const int xc  = tid >> 3;
    const int xn0 = tid & 7;

    for (int kc = 0; kc < DM; kc += 32) {
        {
            us8 v0 = *(const us8*)(wb + (size_t)(o0 + wr) * DM + kc + wc);
            us8 v1 = *(const us8*)(wb + (size_t)(o0 + wr + 64) * DM + kc + wc);
            *(us8*)(&sW[wr * SWS + wc]) = v0;
            *(us8*)(&sW[(wr + 64) * SWS + wc]) = v1;
        }
        {
            const float* xr = xb + (size_t)(kc + xc) * NT;
            #pragma unroll
            for (int j = 0; j < 12; ++j) {
                int n = xn0 + 8 * j;
                float v = (n < NT) ? xr[n] : 0.f;
                sXT[n * SXS + xc] = f2bf(v);
            }
        }
        __syncthreads();
        bf16x8 af0 = ld8(&sW[((wv * 2 + 0) * 16 + r16) * SWS + q8]);
        bf16x8 af1 = ld8(&sW[((wv * 2 + 1) * 16 + r16) * SWS + q8]);
        #pragma unroll
        for (int nt = 0; nt < 6; ++nt) {
            bf16x8 bfr = ld8(&sXT[(nt * 16 + r16) * SXS + q8]);
            acc[0][nt] = __builtin_amdgcn_mfma_f32_16x16x32_bf16(af0, bfr, acc[0][nt], 0, 0, 0);
            acc[1][nt] = __builtin_amdgcn_mfma_f32_16x16x32_bf16(af1, bfr, acc[1][nt], 0, 0, 0);
        }
        __syncthreads();
    }

    unsigned short* qb = qkv + (size_t)b * O3 * NT;
    #pragma unroll
    for (int i = 0; i < 2; ++i) {
        int obase = o0 + (wv * 2 + i) * 16 + (lane >> 4) * 4;
        #pragma unroll
        for (int nt = 0; nt < 6; ++nt) {
            int n = nt * 16 + r16;
            if (n < NT) {
                #pragma unroll
                for (int r = 0; r < 4; ++r) {
                    int o = obase + r;
                    float v = acc[i][nt][r] + bias[o];
                    if (o >= DM && o < 2 * DM) {
                        int oo = o - DM;
                        v += relh[oo * 9 + (n % 9)] + relw[oo * 9 + (n / 9)];
                    }
                    qb[(size_t)o * NT + n] = f2bf(v);
                }
            }
        }
    }
}

// ---------------- kernel 3: attention per (b,h) — v3 ----------------
// 384 threads = 6 waves; wave w owns logit row-tile n in [16w, 16w+16).
// In-register softmax, 2 barriers. NUMERICS = round-0 proven path:
// unnormalized bf16 P, denominator summed from bf16-ROUNDED exps, 1/s applied
// to the fp32 output accumulator (consistent-normalization error cancellation).
// LDS = sQ[96][72] + sK[96][72] (27648 B, dead after QK^T; aliased by
// sP[96][104] = 19968 B + sRcp[96] f32 = 384 B in the slack)
//     + sV[64][104] (13312 B)  => exactly 40960 B => 4 blocks/CU (24 waves).
#define SQS 72    // sQ/sK row stride (u16) = 36 dwords
#define SPS 104   // sP row stride (u16)
#define SVS 104   // sV row stride (u16)

__global__ __launch_bounds__(384, 6) void attn(
    const unsigned short* __restrict__ qkv,
    float* __restrict__ out)
{
    __shared__ __align__(16) unsigned short smem[20480];   // 40960 B
    unsigned short* sQ   = smem;                 // [96][72]
    unsigned short* sK   = smem + 96 * SQS;      // [96][72]
    unsigned short* sP   = smem;                 // [96][104], aliases sQ/sK after barrier 2
    float*          sRcp = (float*)(smem + 96 * SPS);  // 384 B in alias-region slack
    unsigned short* sV   = smem + 2 * 96 * SQS;  // [64][104]

    const int tid  = threadIdx.x;
    const int lane = tid & 63;
    const int wv   = tid >> 6;                 // 0..5 = this wave's n-tile
    const int c    = lane & 15;                // MFMA C col / frag row index
    const int q    = lane >> 4;                // quad
    const int q8   = q * 8;
    const int b    = blockIdx.x >> 3;
    const int h    = blockIdx.x & 7;

    const unsigned short* qp = qkv + (size_t)b * O3 * NT + (size_t)(h * HD) * NT;
    const unsigned short* kp = qp + (size_t)DM * NT;
    const unsigned short* vp = qp + (size_t)(2 * DM) * NT;

    // ---- stage Q,K as [n][d] (u32 = 2 adjacent d), zero-fill n>=81 ----
    {
        const int n   = tid % 96;
        const int d2b = tid / 96;              // 0..3
        #pragma unroll
        for (int i = 0; i < 8; ++i) {
            int d2 = d2b * 8 + i;              // 0..31 (u32 col)
            unsigned q0 = 0, q1 = 0, k0 = 0, k1 = 0;
            if (n < NT) {
                q0 = qp[(2 * d2) * NT + n]; q1 = qp[(2 * d2 + 1) * NT + n];
                k0 = kp[(2 * d2) * NT + n]; k1 = kp[(2 * d2 + 1) * NT + n];
            }
            ((unsigned*)sQ)[n * 36 + d2] = q0 | (q1 << 16);
            ((unsigned*)sK)[n * 36 + d2] = k0 | (k1 << 16);
        }
    }
    // ---- stage V as [d][m] (u32 = 2 adjacent m), zero-fill m>=81 ----
    for (int idx = tid; idx < HD * 52; idx += 384) {
        int d = idx / 52, m2 = idx - d * 52;
        int m0 = 2 * m2;
        unsigned e0 = (m0 < NT)     ? (unsigned)vp[d * NT + m0]     : 0u;
        unsigned e1 = (m0 + 1 < NT) ? (unsigned)vp[d * NT + m0 + 1] : 0u;
        ((unsigned*)sV)[d * 52 + m2] = e0 | (e1 << 16);
    }
    __syncthreads();   // barrier 1: staging complete

    // ---- logits: S[n][m], n-tile = wv, 6 m-tiles, K=64 (2 ksteps) ----
    // acc[mt][r] = S[n = wv*16 + 4q + r][m = mt*16 + c]
    f32x4 acc[6];
    #pragma unroll
    for (int mt = 0; mt < 6; ++mt) acc[mt] = (f32x4){0.f, 0.f, 0.f, 0.f};
    #pragma unroll
    for (int kk = 0; kk < 2; ++kk) {
        bf16x8 qa = ld8(&sQ[(wv * 16 + c) * SQS + kk * 32 + q8]);   // A[row=n][k=d]
        #pragma unroll
        for (int mt = 0; mt < 6; ++mt) {
            bf16x8 kb = ld8(&sK[(mt * 16 + c) * SQS + kk * 32 + q8]); // B[k=d][col=m]
            acc[mt] = __builtin_amdgcn_mfma_f32_16x16x32_bf16(qa, kb, acc[mt], 0, 0, 0);
        }
    }
    // mask pad keys: mt=5 -> m = 80 + c, valid only for c == 0
    #pragma unroll
    for (int r = 0; r < 4; ++r)
        acc[5][r] = (c == 0) ? acc[5][r] : -3.0e38f;

    // ---- in-register softmax over m; acc becomes UNNORMALIZED fp32 exp ----
    // s is accumulated from the bf16-ROUNDED values (matches stored P exactly).
    float rcp[4];
    #pragma unroll
    for (int r = 0; r < 4; ++r) {
        float mx = fmaxf(fmaxf(fmaxf(acc[0][r], acc[1][r]), fmaxf(acc[2][r], acc[3][r])),
                         fmaxf(acc[4][r], acc[5][r]));
        mx = fmaxf(mx, __shfl_xor(mx, 1));
        mx = fmaxf(mx, __shfl_xor(mx, 2));
        mx = fmaxf(mx, __shfl_xor(mx, 4));
        mx = fmaxf(mx, __shfl_xor(mx, 8));
        float s = 0.f;
        #pragma unroll
        for (int mt = 0; mt < 6; ++mt) {
            float e = exp2f((acc[mt][r] - mx) * 1.44269504088896f);  // masked -> 0
            acc[mt][r] = e;
            s += bf2f(f2bf(e));          // sum of quantized values (round-0 numerics)
        }
        s += __shfl_xor(s, 1);
        s += __shfl_xor(s, 2);
        s += __shfl_xor(s, 4);
        s += __shfl_xor(s, 8);
        rcp[r] = 1.0f / s;    // s >= 1 (row max contributes ~1)
    }

    __syncthreads();   // barrier 2: all waves done reading sQ/sK; sP/sRcp may alias

    // ---- write UNNORMALIZED P (bf16) to own rows of sP[n][m]; rcp -> sRcp ----
    #pragma unroll
    for (int mt = 0; mt < 6; ++mt)
        #pragma unroll
        for (int r = 0; r < 4; ++r)
            sP[(wv * 16 + 4 * q + r) * SPS + mt * 16 + c] = f2bf(acc[mt][r]);
    if (c == 0) {
        #pragma unroll
        for (int r = 0; r < 4; ++r)
            sRcp[wv * 16 + 4 * q + r] = rcp[r];
    }
    // own-rows-only: this wave's PV reads exactly the rows it just wrote ->
    // compiler-inserted lgkmcnt suffices, no block barrier.

    // ---- PV: out[d][n] = (sum_m V[d][m] * P[n][m]) * rcp[n]; n-tile = wv ----
    f32x4 oacc[4];
    #pragma unroll
    for (int dt = 0; dt < 4; ++dt) oacc[dt] = (f32x4){0.f, 0.f, 0.f, 0.f};
    #pragma unroll
    for (int kt = 0; kt < 3; ++kt) {
        bf16x8 pb = ld8(&sP[(wv * 16 + c) * SPS + kt * 32 + q8]);   // B[k=m][col=n]
        #pragma unroll
        for (int dt = 0; dt < 4; ++dt) {
            bf16x8 va = ld8(&sV[(dt * 16 + c) * SVS + kt * 32 + q8]); // A[row=d][k=m]
            oacc[dt] = __builtin_amdgcn_mfma_f32_16x16x32_bf16(va, pb, oacc[dt], 0, 0, 0);
        }
    }

    // ---- store: oacc[dt][r] = out[d = dt*16 + 4q + r][n = wv*16 + c] ----
    float* ob = out + (size_t)b * DM * NT + (size_t)(h * HD) * NT;
    const int n = wv * 16 + c;
    if (n < NT) {
        float rs = sRcp[n];
        #pragma unroll
        for (int dt = 0; dt < 4; ++dt) {
            #pragma unroll
            for (int r = 0; r < 4; ++r)
                ob[(size_t)(dt * 16 + 4 * q + r) * NT + n] = oacc[dt][r] * rs;
        }
    }
}

extern "C" void kernel_launch(void* const* d_in, const int* in_sizes, int n_in,
                              void* d_out, int out_size, void* d_ws, size_t ws_size,
                              hipStream_t stream) {
    const float* x     = (const float*)d_in[0];
    const float* qkv_w = (const float*)d_in[1];
    const float* qkv_b = (const float*)d_in[2];
    const float* rel_h = (const float*)d_in[3];
    const float* rel_w = (const float*)d_in[4];
    float* out = (float*)d_out;

    // ws layout: qkv bf16 [1024*1536*81] | wb bf16 [1536*512] | xT bf16 [1024*96*512]
    unsigned short* qkv = (unsigned short*)d_ws;
    unsigned short* wb  = qkv + (size_t)NB * O3 * NT;
    unsigned short* xT  = wb + (size_t)O3 * DM;
    size_t need = ((size_t)NB * O3 * NT + (size_t)O3 * DM + (size_t)NB * NP * DM) * 2;

    conv_w<<<dim3((O3 * DM + 255) / 256), dim3(256), 0, stream>>>(qkv_w, wb, O3 * DM);
    if (ws_size >= need) {
        transpose_x<<<dim3(NB * 8), dim3(256), 0, stream>>>(x, xT);
        qkv_gemm_a<<<dim3(NB * 6), dim3(256), 0, stream>>>(xT, wb, qkv_b, rel_h, rel_w, qkv);
    } else {
        qkv_gemm_fb<<<dim3(NB * 12), dim3(256), 0, stream>>>(x, wb, qkv_b, rel_h, rel_w, qkv);
    }
    attn<<<dim3(NB * NH), dim3(384), 0, stream>>>(qkv, out);
}

// Round 3
// 759.563 us; speedup vs baseline: 1.2831x; 1.0668x over previous
//
#include <hip/hip_runtime.h>
#include <hip/hip_bf16.h>
#include <cstdint>
#include <cstddef>

#define NB 1024
#define DM 512
#define NH 8
#define HD 64
#define NT 81
#define O3 1536
#define NP 96

typedef __bf16 bf16x8 __attribute__((ext_vector_type(8)));
typedef float  f32x4  __attribute__((ext_vector_type(4)));
typedef unsigned short us8 __attribute__((ext_vector_type(8)));

__device__ __forceinline__ unsigned short f2bf(float f) {
    unsigned u = __builtin_bit_cast(unsigned, f);
    u += 0x7fffu + ((u >> 16) & 1u);          // round-to-nearest-even
    return (unsigned short)(u >> 16);
}
__device__ __forceinline__ float bf2f(unsigned short h) {
    unsigned u = ((unsigned)h) << 16;
    return __builtin_bit_cast(float, u);
}
__device__ __forceinline__ bf16x8 ld8(const unsigned short* p) {
    return __builtin_bit_cast(bf16x8, *(const us8*)p);
}
__device__ __forceinline__ void async16(void* lds, const void* g) {
    __builtin_amdgcn_global_load_lds(
        (const __attribute__((address_space(1))) void*)g,
        (__attribute__((address_space(3))) void*)lds, 16, 0, 0);
}

// ---------------- kernel 1: qkv_w fp32 -> bf16 ----------------
__global__ void conv_w(const float* __restrict__ w, unsigned short* __restrict__ wb, int n) {
    int i = blockIdx.x * 256 + threadIdx.x;
    if (i < n) wb[i] = f2bf(w[i]);
}

// ---------------- kernel 1b: x fp32 [b][c][n] -> xT bf16 [b][n=96][c=512] ----------------
__global__ __launch_bounds__(256) void transpose_x(
    const float* __restrict__ x, unsigned short* __restrict__ xT)
{
    __shared__ float sT[64][85];   // stride 85: 2-way (free) banks both phases
    const int tid = threadIdx.x;
    const int b  = blockIdx.x >> 3;
    const int c0 = (blockIdx.x & 7) * 64;
    const float* xb = x + ((size_t)b * DM + c0) * NT;

    const int nn = tid & 31, cc0 = tid >> 5;
    for (int i = 0; i < 8; ++i) {
        int cc = cc0 + i * 8;
        const float* xr = xb + (size_t)cc * NT;
        #pragma unroll
        for (int j = 0; j < 3; ++j) {
            int n = nn + 32 * j;
            if (n < NT) sT[cc][n] = xr[n];
        }
    }
    __syncthreads();

    const int ci = tid & 7, n0 = tid >> 3;    // ci: c-octet, n0: 0..31
    for (int i = 0; i < 3; ++i) {
        int n = n0 + 32 * i;                  // 0..95 (pad rows -> zeros)
        us8 v;
        #pragma unroll
        for (int j = 0; j < 8; ++j) {
            float f = (n < NT) ? sT[ci * 8 + j][n] : 0.f;
            v[j] = f2bf(f);
        }
        *(us8*)(xT + ((size_t)b * NP + n) * DM + c0 + ci * 8) = v;
    }
}

// ---------------- kernel 2a: QKV GEMM — 2-phase dbuf + XOR-swizzled LDS ----------------
// Block tile O=256 x N=96, KC=32, 16 ksteps. Per wave: 4 o-subtiles x 6 n-tiles = 24 MFMA/kstep.
// v4 changes vs v3:
//  (a) double-buffered LDS; next K-tile's global_load_lds issued BEFORE computing the
//      current tile (T3 minimal 2-phase) -> load latency hides under MFMA+ds_read;
//      ONE barrier per kstep (was 2).
//  (b) bank-conflict fix: rows are 64 B (16 banks) so ds_read_b128 was 8-way conflicted.
//      Chunk swizzle cb ^= (row&3), applied on the GLOBAL source (LDS dest stays linear,
//      rule: both-sides-or-neither with global_load_lds) and on the read offset.
//      16 lanes -> 8 chunk-slots x 2 = 2-way (free).
// Numerics bit-identical: same MFMA shape, same ascending-K accumulation order, same data.
#define OT 256
#define KC 32

__global__ __launch_bounds__(256, 3) void qkv_gemm_a(
    const unsigned short* __restrict__ xT,
    const unsigned short* __restrict__ wb,
    const float* __restrict__ bias,
    const float* __restrict__ relh,
    const float* __restrict__ relw,
    unsigned short* __restrict__ qkv)
{
    __shared__ __align__(16) unsigned short sW[2][OT * KC];   // 2 x 16 KB
    __shared__ __align__(16) unsigned short sX[2][NP * KC];   // 2 x 6 KB   => 45056 B total

    const int tid  = threadIdx.x;
    const int lane = tid & 63;
    const int wv   = tid >> 6;
    const int b    = blockIdx.x / 6;
    const int ot   = blockIdx.x % 6;
    const int o0   = ot * OT;
    const int r16  = lane & 15;
    const int q8   = (lane >> 4) * 8;
    const int sq8  = q8 ^ ((r16 & 3) * 8);    // swizzled chunk offset (shorts)

    f32x4 acc[4][6];
    #pragma unroll
    for (int i = 0; i < 4; ++i)
        #pragma unroll
        for (int j = 0; j < 6; ++j)
            acc[i][j] = (f32x4){0.f, 0.f, 0.f, 0.f};

    const unsigned short* xb = xT + (size_t)b * NP * DM;

    // stage one K-tile into buffer bi; global source chunk pre-swizzled by row&3
    auto stage = [&](int bi, int kc) {
        unsigned short* dW = &sW[bi][0];
        unsigned short* dX = &sX[bi][0];
        #pragma unroll
        for (int i = 0; i < 4; ++i) {
            int ch  = i * 256 + wv * 64 + lane;
            int row = ch >> 2, cb = ch & 3;
            int cbs = cb ^ (row & 3);
            async16(dW + (i * 256 + wv * 64) * 8,
                    wb + (size_t)(o0 + row) * DM + kc + cbs * 8);
        }
        {
            int ch  = wv * 64 + lane;
            int row = ch >> 2, cb = ch & 3;
            int cbs = cb ^ (row & 3);
            async16(dX + (wv * 64) * 8, xb + (size_t)row * DM + kc + cbs * 8);
            if (wv < 2) {
                int ch2  = 256 + wv * 64 + lane;
                int row2 = ch2 >> 2, cb2 = ch2 & 3;
                int cbs2 = cb2 ^ (row2 & 3);
                async16(dX + (256 + wv * 64) * 8, xb + (size_t)row2 * DM + kc + cbs2 * 8);
            }
        }
    };

    auto compute = [&](const unsigned short* bW, const unsigned short* bX) {
        bf16x8 af[4], bfr[6];
        #pragma unroll
        for (int i = 0; i < 4; ++i)
            af[i] = ld8(&bW[(wv * 64 + i * 16 + r16) * KC + sq8]);
        #pragma unroll
        for (int nt = 0; nt < 6; ++nt)
            bfr[nt] = ld8(&bX[(nt * 16 + r16) * KC + sq8]);
        #pragma unroll
        for (int i = 0; i < 4; ++i)
            #pragma unroll
            for (int nt = 0; nt < 6; ++nt)
                acc[i][nt] = __builtin_amdgcn_mfma_f32_16x16x32_bf16(af[i], bfr[nt], acc[i][nt], 0, 0, 0);
    };

    stage(0, 0);
    __syncthreads();                       // buf0 ready (vmcnt(0) drained by barrier)
    for (int ks = 0; ks < 16; ks += 2) {
        stage(1, (ks + 1) * KC);           // prefetch next tile into buf1
        compute(&sW[0][0], &sX[0][0]);     // compute current tile (buf0)
        __syncthreads();                   // drains prefetch -> buf1 ready
        if (ks + 2 < 16) stage(0, (ks + 2) * KC);
        compute(&sW[1][0], &sX[1][0]);
        __syncthreads();
    }

    unsigned short* qb = qkv + (size_t)b * O3 * NT;
    #pragma unroll
    for (int i = 0; i < 4; ++i) {
        int obase = o0 + (wv * 4 + i) * 16 + (lane >> 4) * 4;   // C/D row = quad*4+reg
        #pragma unroll
        for (int nt = 0; nt < 6; ++nt) {
            int n = nt * 16 + r16;                               // C/D col
            if (n < NT) {
                #pragma unroll
                for (int r = 0; r < 4; ++r) {
                    int o = obase + r;
                    float v = acc[i][nt][r] + bias[o];
                    if (o >= DM && o < 2 * DM) {                 // K section: fold rel
                        int oo = o - DM;
                        v += relh[oo * 9 + (n % 9)] + relw[oo * 9 + (n / 9)];
                    }
                    qb[(size_t)o * NT + n] = f2bf(v);
                }
            }
        }
    }
}

// ---------------- kernel 2b: fallback GEMM (round-1 verbatim, proven) ----------------
#define OTILE 128
#define SWS 40
#define SXS 40

__global__ __launch_bounds__(256) void qkv_gemm_fb(
    const float* __restrict__ x,
    const unsigned short* __restrict__ wb,
    const float* __restrict__ bias,
    const float* __restrict__ relh,
    const float* __restrict__ relw,
    unsigned short* __restrict__ qkv)
{
    __shared__ unsigned short sW[OTILE * SWS];
    __shared__ unsigned short sXT[NP * SXS];

    const int tid  = threadIdx.x;
    const int lane = tid & 63;
    const int wv   = tid >> 6;
    const int b    = blockIdx.x / (O3 / OTILE);
    const int ot   = blockIdx.x % (O3 / OTILE);
    const int o0   = ot * OTILE;
    const int r16 = lane & 15;
    const int q8  = (lane >> 4) * 8;

    f32x4 acc[2][6];
    for (int i = 0; i < 2; ++i)
        for (int j = 0; j < 6; ++j)
            acc[i][j] = (f32x4){0.f, 0.f, 0.f, 0.f};

    const float* xb = x + (size_t)b * DM * NT;
    const int wr  = tid >> 2;
    const int wc  = (tid & 3) * 8;
    const int xc  = tid >> 3;
    const int xn0 = tid & 7;

    for (int kc = 0; kc < DM; kc += 32) {
        {
            us8 v0 = *(const us8*)(wb + (size_t)(o0 + wr) * DM + kc + wc);
            us8 v1 = *(const us8*)(wb + (size_t)(o0 + wr + 64) * DM + kc + wc);
            *(us8*)(&sW[wr * SWS + wc]) = v0;
            *(us8*)(&sW[(wr + 64) * SWS + wc]) = v1;
        }
        {
            const float* xr = xb + (size_t)(kc + xc) * NT;
            #pragma unroll
            for (int j = 0; j < 12; ++j) {
                int n = xn0 + 8 * j;
                float v = (n < NT) ? xr[n] : 0.f;
                sXT[n * SXS + xc] = f2bf(v);
            }
        }
        __syncthreads();
        bf16x8 af0 = ld8(&sW[((wv * 2 + 0) * 16 + r16) * SWS + q8]);
        bf16x8 af1 = ld8(&sW[((wv * 2 + 1) * 16 + r16) * SWS + q8]);
        #pragma unroll
        for (int nt = 0; nt < 6; ++nt) {
            bf16x8 bfr = ld8(&sXT[(nt * 16 + r16) * SXS + q8]);
            acc[0][nt] = __builtin_amdgcn_mfma_f32_16x16x32_bf16(af0, bfr, acc[0][nt], 0, 0, 0);
            acc[1][nt] = __builtin_amdgcn_mfma_f32_16x16x32_bf16(af1, bfr, acc[1][nt], 0, 0, 0);
        }
        __syncthreads();
    }

    unsigned short* qb = qkv + (size_t)b * O3 * NT;
    #pragma unroll
    for (int i = 0; i < 2; ++i) {
        int obase = o0 + (wv * 2 + i) * 16 + (lane >> 4) * 4;
        #pragma unroll
        for (int nt = 0; nt < 6; ++nt) {
            int n = nt * 16 + r16;
            if (n < NT) {
                #pragma unroll
                for (int r = 0; r < 4; ++r) {
                    int o = obase + r;
                    float v = acc[i][nt][r] + bias[o];
                    if (o >= DM && o < 2 * DM) {
                        int oo = o - DM;
                        v += relh[oo * 9 + (n % 9)] + relw[oo * 9 + (n / 9)];
                    }
                    qb[(size_t)o * NT + n] = f2bf(v);
                }
            }
        }
    }
}

// ---------------- kernel 3: attention per (b,h) — v3 (proven round 2) ----------------
#define SQS 72    // sQ/sK row stride (u16) = 36 dwords
#define SPS 104   // sP row stride (u16)
#define SVS 104   // sV row stride (u16)

__global__ __launch_bounds__(384, 6) void attn(
    const unsigned short* __restrict__ qkv,
    float* __restrict__ out)
{
    __shared__ __align__(16) unsigned short smem[20480];   // 40960 B
    unsigned short* sQ   = smem;                 // [96][72]
    unsigned short* sK   = smem + 96 * SQS;      // [96][72]
    unsigned short* sP   = smem;                 // [96][104], aliases sQ/sK after barrier 2
    float*          sRcp = (float*)(smem + 96 * SPS);  // 384 B in alias-region slack
    unsigned short* sV   = smem + 2 * 96 * SQS;  // [64][104]

    const int tid  = threadIdx.x;
    const int lane = tid & 63;
    const int wv   = tid >> 6;                 // 0..5 = this wave's n-tile
    const int c    = lane & 15;                // MFMA C col / frag row index
    const int q    = lane >> 4;                // quad
    const int q8   = q * 8;
    const int b    = blockIdx.x >> 3;
    const int h    = blockIdx.x & 7;

    const unsigned short* qp = qkv + (size_t)b * O3 * NT + (size_t)(h * HD) * NT;
    const unsigned short* kp = qp + (size_t)DM * NT;
    const unsigned short* vp = qp + (size_t)(2 * DM) * NT;

    // ---- stage Q,K as [n][d] (u32 = 2 adjacent d), zero-fill n>=81 ----
    {
        const int n   = tid % 96;
        const int d2b = tid / 96;              // 0..3
        #pragma unroll
        for (int i = 0; i < 8; ++i) {
            int d2 = d2b * 8 + i;              // 0..31 (u32 col)
            unsigned q0 = 0, q1 = 0, k0 = 0, k1 = 0;
            if (n < NT) {
                q0 = qp[(2 * d2) * NT + n]; q1 = qp[(2 * d2 + 1) * NT + n];
                k0 = kp[(2 * d2) * NT + n]; k1 = kp[(2 * d2 + 1) * NT + n];
            }
            ((unsigned*)sQ)[n * 36 + d2] = q0 | (q1 << 16);
            ((unsigned*)sK)[n * 36 + d2] = k0 | (k1 << 16);
        }
    }
    // ---- stage V as [d][m] (u32 = 2 adjacent m), zero-fill m>=81 ----
    for (int idx = tid; idx < HD * 52; idx += 384) {
        int d = idx / 52, m2 = idx - d * 52;
        int m0 = 2 * m2;
        unsigned e0 = (m0 < NT)     ? (unsigned)vp[d * NT + m0]     : 0u;
        unsigned e1 = (m0 + 1 < NT) ? (unsigned)vp[d * NT + m0 + 1] : 0u;
        ((unsigned*)sV)[d * 52 + m2] = e0 | (e1 << 16);
    }
    __syncthreads();   // barrier 1: staging complete

    // ---- logits: S[n][m], n-tile = wv, 6 m-tiles, K=64 (2 ksteps) ----
    f32x4 acc[6];
    #pragma unroll
    for (int mt = 0; mt < 6; ++mt) acc[mt] = (f32x4){0.f, 0.f, 0.f, 0.f};
    #pragma unroll
    for (int kk = 0; kk < 2; ++kk) {
        bf16x8 qa = ld8(&sQ[(wv * 16 + c) * SQS + kk * 32 + q8]);   // A[row=n][k=d]
        #pragma unroll
        for (int mt = 0; mt < 6; ++mt) {
            bf16x8 kb = ld8(&sK[(mt * 16 + c) * SQS + kk * 32 + q8]); // B[k=d][col=m]
            acc[mt] = __builtin_amdgcn_mfma_f32_16x16x32_bf16(qa, kb, acc[mt], 0, 0, 0);
        }
    }
    // mask pad keys: mt=5 -> m = 80 + c, valid only for c == 0
    #pragma unroll
    for (int r = 0; r < 4; ++r)
        acc[5][r] = (c == 0) ? acc[5][r] : -3.0e38f;

    // ---- in-register softmax over m; acc becomes UNNORMALIZED fp32 exp ----
    float rcp[4];
    #pragma unroll
    for (int r = 0; r < 4; ++r) {
        float mx = fmaxf(fmaxf(fmaxf(acc[0][r], acc[1][r]), fmaxf(acc[2][r], acc[3][r])),
                         fmaxf(acc[4][r], acc[5][r]));
        mx = fmaxf(mx, __shfl_xor(mx, 1));
        mx = fmaxf(mx, __shfl_xor(mx, 2));
        mx = fmaxf(mx, __shfl_xor(mx, 4));
        mx = fmaxf(mx, __shfl_xor(mx, 8));
        float s = 0.f;
        #pragma unroll
        for (int mt = 0; mt < 6; ++mt) {
            float e = exp2f((acc[mt][r] - mx) * 1.44269504088896f);  // masked -> 0
            acc[mt][r] = e;
            s += bf2f(f2bf(e));          // sum of quantized values (round-0 numerics)
        }
        s += __shfl_xor(s, 1);
        s += __shfl_xor(s, 2);
        s += __shfl_xor(s, 4);
        s += __shfl_xor(s, 8);
        rcp[r] = 1.0f / s;    // s >= 1 (row max contributes ~1)
    }

    __syncthreads();   // barrier 2: all waves done reading sQ/sK; sP/sRcp may alias

    // ---- write UNNORMALIZED P (bf16) to own rows of sP[n][m]; rcp -> sRcp ----
    #pragma unroll
    for (int mt = 0; mt < 6; ++mt)
        #pragma unroll
        for (int r = 0; r < 4; ++r)
            sP[(wv * 16 + 4 * q + r) * SPS + mt * 16 + c] = f2bf(acc[mt][r]);
    if (c == 0) {
        #pragma unroll
        for (int r = 0; r < 4; ++r)
            sRcp[wv * 16 + 4 * q + r] = rcp[r];
    }
    // own-rows-only: this wave's PV reads exactly the rows it just wrote ->
    // compiler-inserted lgkmcnt suffices, no block barrier.

    // ---- PV: out[d][n] = (sum_m V[d][m] * P[n][m]) * rcp[n]; n-tile = wv ----
    f32x4 oacc[4];
    #pragma unroll
    for (int dt = 0; dt < 4; ++dt) oacc[dt] = (f32x4){0.f, 0.f, 0.f, 0.f};
    #pragma unroll
    for (int kt = 0; kt < 3; ++kt) {
        bf16x8 pb = ld8(&sP[(wv * 16 + c) * SPS + kt * 32 + q8]);   // B[k=m][col=n]
        #pragma unroll
        for (int dt = 0; dt < 4; ++dt) {
            bf16x8 va = ld8(&sV[(dt * 16 + c) * SVS + kt * 32 + q8]); // A[row=d][k=m]
            oacc[dt] = __builtin_amdgcn_mfma_f32_16x16x32_bf16(va, pb, oacc[dt], 0, 0, 0);
        }
    }

    // ---- store: oacc[dt][r] = out[d = dt*16 + 4q + r][n = wv*16 + c] ----
    float* ob = out + (size_t)b * DM * NT + (size_t)(h * HD) * NT;
    const int n = wv * 16 + c;
    if (n < NT) {
        float rs = sRcp[n];
        #pragma unroll
        for (int dt = 0; dt < 4; ++dt) {
            #pragma unroll
            for (int r = 0; r < 4; ++r)
                ob[(size_t)(dt * 16 + 4 * q + r) * NT + n] = oacc[dt][r] * rs;
        }
    }
}

extern "C" void kernel_launch(void* const* d_in, const int* in_sizes, int n_in,
                              void* d_out, int out_size, void* d_ws, size_t ws_size,
                              hipStream_t stream) {
    const float* x     = (const float*)d_in[0];
    const float* qkv_w = (const float*)d_in[1];
    const float* qkv_b = (const float*)d_in[2];
    const float* rel_h = (const float*)d_in[3];
    const float* rel_w = (const float*)d_in[4];
    float* out = (float*)d_out;

    // ws layout: qkv bf16 [1024*1536*81] | wb bf16 [1536*512] | xT bf16 [1024*96*512]
    unsigned short* qkv = (unsigned short*)d_ws;
    unsigned short* wb  = qkv + (size_t)NB * O3 * NT;
    unsigned short* xT  = wb + (size_t)O3 * DM;
    size_t need = ((size_t)NB * O3 * NT + (size_t)O3 * DM + (size_t)NB * NP * DM) * 2;

    conv_w<<<dim3((O3 * DM + 255) / 256), dim3(256), 0, stream>>>(qkv_w, wb, O3 * DM);
    if (ws_size >= need) {
        transpose_x<<<dim3(NB * 8), dim3(256), 0, stream>>>(x, xT);
        qkv_gemm_a<<<dim3(NB * 6), dim3(256), 0, stream>>>(xT, wb, qkv_b, rel_h, rel_w, qkv);
    } else {
        qkv_gemm_fb<<<dim3(NB * 12), dim3(256), 0, stream>>>(x, wb, qkv_b, rel_h, rel_w, qkv);
    }
    attn<<<dim3(NB * NH), dim3(384), 0, stream>>>(qkv, out);
}

// Round 4
// 754.969 us; speedup vs baseline: 1.2909x; 1.0061x over previous
//
#include <hip/hip_runtime.h>
#include <hip/hip_bf16.h>
#include <cstdint>
#include <cstddef>

#define NB 1024
#define DM 512
#define NH 8
#define HD 64
#define NT 81
#define O3 1536
#define NP 96

typedef __bf16 bf16x8 __attribute__((ext_vector_type(8)));
typedef float  f32x4  __attribute__((ext_vector_type(4)));
typedef unsigned short us8 __attribute__((ext_vector_type(8)));

__device__ __forceinline__ unsigned short f2bf(float f) {
    unsigned u = __builtin_bit_cast(unsigned, f);
    u += 0x7fffu + ((u >> 16) & 1u);          // round-to-nearest-even
    return (unsigned short)(u >> 16);
}
__device__ __forceinline__ float bf2f(unsigned short h) {
    unsigned u = ((unsigned)h) << 16;
    return __builtin_bit_cast(float, u);
}
__device__ __forceinline__ bf16x8 ld8(const unsigned short* p) {
    return __builtin_bit_cast(bf16x8, *(const us8*)p);
}
__device__ __forceinline__ void async16(void* lds, const void* g) {
    __builtin_amdgcn_global_load_lds(
        (const __attribute__((address_space(1))) void*)g,
        (__attribute__((address_space(3))) void*)lds, 16, 0, 0);
}

// ---------------- kernel 1: qkv_w fp32 -> bf16 ----------------
__global__ void conv_w(const float* __restrict__ w, unsigned short* __restrict__ wb, int n) {
    int i = blockIdx.x * 256 + threadIdx.x;
    if (i < n) wb[i] = f2bf(w[i]);
}

// ---------------- kernel 1b: x fp32 [b][c][n] -> xT bf16 [b][n=96][c=512] ----------------
__global__ __launch_bounds__(256) void transpose_x(
    const float* __restrict__ x, unsigned short* __restrict__ xT)
{
    __shared__ float sT[64][85];   // stride 85: 2-way (free) banks both phases
    const int tid = threadIdx.x;
    const int b  = blockIdx.x >> 3;
    const int c0 = (blockIdx.x & 7) * 64;
    const float* xb = x + ((size_t)b * DM + c0) * NT;

    const int nn = tid & 31, cc0 = tid >> 5;
    for (int i = 0; i < 8; ++i) {
        int cc = cc0 + i * 8;
        const float* xr = xb + (size_t)cc * NT;
        #pragma unroll
        for (int j = 0; j < 3; ++j) {
            int n = nn + 32 * j;
            if (n < NT) sT[cc][n] = xr[n];
        }
    }
    __syncthreads();

    const int ci = tid & 7, n0 = tid >> 3;    // ci: c-octet, n0: 0..31
    for (int i = 0; i < 3; ++i) {
        int n = n0 + 32 * i;                  // 0..95 (pad rows -> zeros)
        us8 v;
        #pragma unroll
        for (int j = 0; j < 8; ++j) {
            float f = (n < NT) ? sT[ci * 8 + j][n] : 0.f;
            v[j] = f2bf(f);
        }
        *(us8*)(xT + ((size_t)b * NP + n) * DM + c0 + ci * 8) = v;
    }
}

// ---------------- kernel 2a: QKV GEMM — dbuf + XCD-chunked swizzle ----------------
// Block tile O=256 x N=96, KC=32, 16 ksteps. Per wave: 4 o-subtiles x 6 n-tiles = 24 MFMA/kstep.
// v5 change vs v4: XCD-chunked block swizzle (T1). HW maps dispatch index D -> XCD D%8;
// we assign b = (D%8)*128 + (D/8)/6, ot = (D/8)%6 so the 6 blocks sharing one xT panel
// run CONSECUTIVELY ON THE SAME XCD: panel fetched from HBM once, 5 L2 hits after.
// Working set per XCD ~ W(1.5MB) + live panels(~1.5MB) < 4MB L2. Bijective: 6144 = 8*128*6.
// Numerics bit-identical (index remap only).
#define OT 256
#define KC 32

__global__ __launch_bounds__(256, 3) void qkv_gemm_a(
    const unsigned short* __restrict__ xT,
    const unsigned short* __restrict__ wb,
    const float* __restrict__ bias,
    const float* __restrict__ relh,
    const float* __restrict__ relw,
    unsigned short* __restrict__ qkv)
{
    __shared__ __align__(16) unsigned short sW[2][OT * KC];   // 2 x 16 KB
    __shared__ __align__(16) unsigned short sX[2][NP * KC];   // 2 x 6 KB   => 45056 B total

    const int tid  = threadIdx.x;
    const int lane = tid & 63;
    const int wv   = tid >> 6;
    // XCD-chunked swizzle: D%8 = XCD (HW round-robin), 128 consecutive b per XCD,
    // all 6 o-tiles of one b adjacent in the per-XCD sequence.
    const int D    = blockIdx.x;
    const int s    = D >> 3;                  // per-XCD sequence 0..767
    const int b    = (D & 7) * (NB / 8) + s / 6;
    const int ot   = s % 6;
    const int o0   = ot * OT;
    const int r16  = lane & 15;
    const int q8   = (lane >> 4) * 8;
    const int sq8  = q8 ^ ((r16 & 3) * 8);    // swizzled chunk offset (shorts)

    f32x4 acc[4][6];
    #pragma unroll
    for (int i = 0; i < 4; ++i)
        #pragma unroll
        for (int j = 0; j < 6; ++j)
            acc[i][j] = (f32x4){0.f, 0.f, 0.f, 0.f};

    const unsigned short* xb = xT + (size_t)b * NP * DM;

    // stage one K-tile into buffer bi; global source chunk pre-swizzled by row&3
    auto stage = [&](int bi, int kc) {
        unsigned short* dW = &sW[bi][0];
        unsigned short* dX = &sX[bi][0];
        #pragma unroll
        for (int i = 0; i < 4; ++i) {
            int ch  = i * 256 + wv * 64 + lane;
            int row = ch >> 2, cb = ch & 3;
            int cbs = cb ^ (row & 3);
            async16(dW + (i * 256 + wv * 64) * 8,
                    wb + (size_t)(o0 + row) * DM + kc + cbs * 8);
        }
        {
            int ch  = wv * 64 + lane;
            int row = ch >> 2, cb = ch & 3;
            int cbs = cb ^ (row & 3);
            async16(dX + (wv * 64) * 8, xb + (size_t)row * DM + kc + cbs * 8);
            if (wv < 2) {
                int ch2  = 256 + wv * 64 + lane;
                int row2 = ch2 >> 2, cb2 = ch2 & 3;
                int cbs2 = cb2 ^ (row2 & 3);
                async16(dX + (256 + wv * 64) * 8, xb + (size_t)row2 * DM + kc + cbs2 * 8);
            }
        }
    };

    auto compute = [&](const unsigned short* bW, const unsigned short* bX) {
        bf16x8 af[4], bfr[6];
        #pragma unroll
        for (int i = 0; i < 4; ++i)
            af[i] = ld8(&bW[(wv * 64 + i * 16 + r16) * KC + sq8]);
        #pragma unroll
        for (int nt = 0; nt < 6; ++nt)
            bfr[nt] = ld8(&bX[(nt * 16 + r16) * KC + sq8]);
        #pragma unroll
        for (int i = 0; i < 4; ++i)
            #pragma unroll
            for (int nt = 0; nt < 6; ++nt)
                acc[i][nt] = __builtin_amdgcn_mfma_f32_16x16x32_bf16(af[i], bfr[nt], acc[i][nt], 0, 0, 0);
    };

    stage(0, 0);
    __syncthreads();                       // buf0 ready (vmcnt(0) drained by barrier)
    for (int ks = 0; ks < 16; ks += 2) {
        stage(1, (ks + 1) * KC);           // prefetch next tile into buf1
        compute(&sW[0][0], &sX[0][0]);     // compute current tile (buf0)
        __syncthreads();                   // drains prefetch -> buf1 ready
        if (ks + 2 < 16) stage(0, (ks + 2) * KC);
        compute(&sW[1][0], &sX[1][0]);
        __syncthreads();
    }

    unsigned short* qb = qkv + (size_t)b * O3 * NT;
    #pragma unroll
    for (int i = 0; i < 4; ++i) {
        int obase = o0 + (wv * 4 + i) * 16 + (lane >> 4) * 4;   // C/D row = quad*4+reg
        #pragma unroll
        for (int nt = 0; nt < 6; ++nt) {
            int n = nt * 16 + r16;                               // C/D col
            if (n < NT) {
                #pragma unroll
                for (int r = 0; r < 4; ++r) {
                    int o = obase + r;
                    float v = acc[i][nt][r] + bias[o];
                    if (o >= DM && o < 2 * DM) {                 // K section: fold rel
                        int oo = o - DM;
                        v += relh[oo * 9 + (n % 9)] + relw[oo * 9 + (n / 9)];
                    }
                    qb[(size_t)o * NT + n] = f2bf(v);
                }
            }
        }
    }
}

// ---------------- kernel 2b: fallback GEMM (round-1 verbatim, proven) ----------------
#define OTILE 128
#define SWS 40
#define SXS 40

__global__ __launch_bounds__(256) void qkv_gemm_fb(
    const float* __restrict__ x,
    const unsigned short* __restrict__ wb,
    const float* __restrict__ bias,
    const float* __restrict__ relh,
    const float* __restrict__ relw,
    unsigned short* __restrict__ qkv)
{
    __shared__ unsigned short sW[OTILE * SWS];
    __shared__ unsigned short sXT[NP * SXS];

    const int tid  = threadIdx.x;
    const int lane = tid & 63;
    const int wv   = tid >> 6;
    const int b    = blockIdx.x / (O3 / OTILE);
    const int ot   = blockIdx.x % (O3 / OTILE);
    const int o0   = ot * OTILE;
    const int r16 = lane & 15;
    const int q8  = (lane >> 4) * 8;

    f32x4 acc[2][6];
    for (int i = 0; i < 2; ++i)
        for (int j = 0; j < 6; ++j)
            acc[i][j] = (f32x4){0.f, 0.f, 0.f, 0.f};

    const float* xb = x + (size_t)b * DM * NT;
    const int wr  = tid >> 2;
    const int wc  = (tid & 3) * 8;
    const int xc  = tid >> 3;
    const int xn0 = tid & 7;

    for (int kc = 0; kc < DM; kc += 32) {
        {
            us8 v0 = *(const us8*)(wb + (size_t)(o0 + wr) * DM + kc + wc);
            us8 v1 = *(const us8*)(wb + (size_t)(o0 + wr + 64) * DM + kc + wc);
            *(us8*)(&sW[wr * SWS + wc]) = v0;
            *(us8*)(&sW[(wr + 64) * SWS + wc]) = v1;
        }
        {
            const float* xr = xb + (size_t)(kc + xc) * NT;
            #pragma unroll
            for (int j = 0; j < 12; ++j) {
                int n = xn0 + 8 * j;
                float v = (n < NT) ? xr[n] : 0.f;
                sXT[n * SXS + xc] = f2bf(v);
            }
        }
        __syncthreads();
        bf16x8 af0 = ld8(&sW[((wv * 2 + 0) * 16 + r16) * SWS + q8]);
        bf16x8 af1 = ld8(&sW[((wv * 2 + 1) * 16 + r16) * SWS + q8]);
        #pragma unroll
        for (int nt = 0; nt < 6; ++nt) {
            bf16x8 bfr = ld8(&sXT[(nt * 16 + r16) * SXS + q8]);
            acc[0][nt] = __builtin_amdgcn_mfma_f32_16x16x32_bf16(af0, bfr, acc[0][nt], 0, 0, 0);
            acc[1][nt] = __builtin_amdgcn_mfma_f32_16x16x32_bf16(af1, bfr, acc[1][nt], 0, 0, 0);
        }
        __syncthreads();
    }

    unsigned short* qb = qkv + (size_t)b * O3 * NT;
    #pragma unroll
    for (int i = 0; i < 2; ++i) {
        int obase = o0 + (wv * 2 + i) * 16 + (lane >> 4) * 4;
        #pragma unroll
        for (int nt = 0; nt < 6; ++nt) {
            int n = nt * 16 + r16;
            if (n < NT) {
                #pragma unroll
                for (int r = 0; r < 4; ++r) {
                    int o = obase + r;
                    float v = acc[i][nt][r] + bias[o];
                    if (o >= DM && o < 2 * DM) {
                        int oo = o - DM;
                        v += relh[oo * 9 + (n % 9)] + relw[oo * 9 + (n / 9)];
                    }
                    qb[(size_t)o * NT + n] = f2bf(v);
                }
            }
        }
    }
}

// ---------------- kernel 3: attention per (b,h) — v3 (proven round 2) ----------------
#define SQS 72    // sQ/sK row stride (u16) = 36 dwords
#define SPS 104   // sP row stride (u16)
#define SVS 104   // sV row stride (u16)

__global__ __launch_bounds__(384, 6) void attn(
    const unsigned short* __restrict__ qkv,
    float* __restrict__ out)
{
    __shared__ __align__(16) unsigned short smem[20480];   // 40960 B
    unsigned short* sQ   = smem;                 // [96][72]
    unsigned short* sK   = smem + 96 * SQS;      // [96][72]
    unsigned short* sP   = smem;                 // [96][104], aliases sQ/sK after barrier 2
    float*          sRcp = (float*)(smem + 96 * SPS);  // 384 B in alias-region slack
    unsigned short* sV   = smem + 2 * 96 * SQS;  // [64][104]

    const int tid  = threadIdx.x;
    const int lane = tid & 63;
    const int wv   = tid >> 6;                 // 0..5 = this wave's n-tile
    const int c    = lane & 15;                // MFMA C col / frag row index
    const int q    = lane >> 4;                // quad
    const int q8   = q * 8;
    const int b    = blockIdx.x >> 3;
    const int h    = blockIdx.x & 7;

    const unsigned short* qp = qkv + (size_t)b * O3 * NT + (size_t)(h * HD) * NT;
    const unsigned short* kp = qp + (size_t)DM * NT;
    const unsigned short* vp = qp + (size_t)(2 * DM) * NT;

    // ---- stage Q,K as [n][d] (u32 = 2 adjacent d), zero-fill n>=81 ----
    {
        const int n   = tid % 96;
        const int d2b = tid / 96;              // 0..3
        #pragma unroll
        for (int i = 0; i < 8; ++i) {
            int d2 = d2b * 8 + i;              // 0..31 (u32 col)
            unsigned q0 = 0, q1 = 0, k0 = 0, k1 = 0;
            if (n < NT) {
                q0 = qp[(2 * d2) * NT + n]; q1 = qp[(2 * d2 + 1) * NT + n];
                k0 = kp[(2 * d2) * NT + n]; k1 = kp[(2 * d2 + 1) * NT + n];
            }
            ((unsigned*)sQ)[n * 36 + d2] = q0 | (q1 << 16);
            ((unsigned*)sK)[n * 36 + d2] = k0 | (k1 << 16);
        }
    }
    // ---- stage V as [d][m] (u32 = 2 adjacent m), zero-fill m>=81 ----
    for (int idx = tid; idx < HD * 52; idx += 384) {
        int d = idx / 52, m2 = idx - d * 52;
        int m0 = 2 * m2;
        unsigned e0 = (m0 < NT)     ? (unsigned)vp[d * NT + m0]     : 0u;
        unsigned e1 = (m0 + 1 < NT) ? (unsigned)vp[d * NT + m0 + 1] : 0u;
        ((unsigned*)sV)[d * 52 + m2] = e0 | (e1 << 16);
    }
    __syncthreads();   // barrier 1: staging complete

    // ---- logits: S[n][m], n-tile = wv, 6 m-tiles, K=64 (2 ksteps) ----
    f32x4 acc[6];
    #pragma unroll
    for (int mt = 0; mt < 6; ++mt) acc[mt] = (f32x4){0.f, 0.f, 0.f, 0.f};
    #pragma unroll
    for (int kk = 0; kk < 2; ++kk) {
        bf16x8 qa = ld8(&sQ[(wv * 16 + c) * SQS + kk * 32 + q8]);   // A[row=n][k=d]
        #pragma unroll
        for (int mt = 0; mt < 6; ++mt) {
            bf16x8 kb = ld8(&sK[(mt * 16 + c) * SQS + kk * 32 + q8]); // B[k=d][col=m]
            acc[mt] = __builtin_amdgcn_mfma_f32_16x16x32_bf16(qa, kb, acc[mt], 0, 0, 0);
        }
    }
    // mask pad keys: mt=5 -> m = 80 + c, valid only for c == 0
    #pragma unroll
    for (int r = 0; r < 4; ++r)
        acc[5][r] = (c == 0) ? acc[5][r] : -3.0e38f;

    // ---- in-register softmax over m; acc becomes UNNORMALIZED fp32 exp ----
    float rcp[4];
    #pragma unroll
    for (int r = 0; r < 4; ++r) {
        float mx = fmaxf(fmaxf(fmaxf(acc[0][r], acc[1][r]), fmaxf(acc[2][r], acc[3][r])),
                         fmaxf(acc[4][r], acc[5][r]));
        mx = fmaxf(mx, __shfl_xor(mx, 1));
        mx = fmaxf(mx, __shfl_xor(mx, 2));
        mx = fmaxf(mx, __shfl_xor(mx, 4));
        mx = fmaxf(mx, __shfl_xor(mx, 8));
        float s = 0.f;
        #pragma unroll
        for (int mt = 0; mt < 6; ++mt) {
            float e = exp2f((acc[mt][r] - mx) * 1.44269504088896f);  // masked -> 0
            acc[mt][r] = e;
            s += bf2f(f2bf(e));          // sum of quantized values (round-0 numerics)
        }
        s += __shfl_xor(s, 1);
        s += __shfl_xor(s, 2);
        s += __shfl_xor(s, 4);
        s += __shfl_xor(s, 8);
        rcp[r] = 1.0f / s;    // s >= 1 (row max contributes ~1)
    }

    __syncthreads();   // barrier 2: all waves done reading sQ/sK; sP/sRcp may alias

    // ---- write UNNORMALIZED P (bf16) to own rows of sP[n][m]; rcp -> sRcp ----
    #pragma unroll
    for (int mt = 0; mt < 6; ++mt)
        #pragma unroll
        for (int r = 0; r < 4; ++r)
            sP[(wv * 16 + 4 * q + r) * SPS + mt * 16 + c] = f2bf(acc[mt][r]);
    if (c == 0) {
        #pragma unroll
        for (int r = 0; r < 4; ++r)
            sRcp[wv * 16 + 4 * q + r] = rcp[r];
    }
    // own-rows-only: this wave's PV reads exactly the rows it just wrote ->
    // compiler-inserted lgkmcnt suffices, no block barrier.

    // ---- PV: out[d][n] = (sum_m V[d][m] * P[n][m]) * rcp[n]; n-tile = wv ----
    f32x4 oacc[4];
    #pragma unroll
    for (int dt = 0; dt < 4; ++dt) oacc[dt] = (f32x4){0.f, 0.f, 0.f, 0.f};
    #pragma unroll
    for (int kt = 0; kt < 3; ++kt) {
        bf16x8 pb = ld8(&sP[(wv * 16 + c) * SPS + kt * 32 + q8]);   // B[k=m][col=n]
        #pragma unroll
        for (int dt = 0; dt < 4; ++dt) {
            bf16x8 va = ld8(&sV[(dt * 16 + c) * SVS + kt * 32 + q8]); // A[row=d][k=m]
            oacc[dt] = __builtin_amdgcn_mfma_f32_16x16x32_bf16(va, pb, oacc[dt], 0, 0, 0);
        }
    }

    // ---- store: oacc[dt][r] = out[d = dt*16 + 4q + r][n = wv*16 + c] ----
    float* ob = out + (size_t)b * DM * NT + (size_t)(h * HD) * NT;
    const int n = wv * 16 + c;
    if (n < NT) {
        float rs = sRcp[n];
        #pragma unroll
        for (int dt = 0; dt < 4; ++dt) {
            #pragma unroll
            for (int r = 0; r < 4; ++r)
                ob[(size_t)(dt * 16 + 4 * q + r) * NT + n] = oacc[dt][r] * rs;
        }
    }
}

extern "C" void kernel_launch(void* const* d_in, const int* in_sizes, int n_in,
                              void* d_out, int out_size, void* d_ws, size_t ws_size,
                              hipStream_t stream) {
    const float* x     = (const float*)d_in[0];
    const float* qkv_w = (const float*)d_in[1];
    const float* qkv_b = (const float*)d_in[2];
    const float* rel_h = (const float*)d_in[3];
    const float* rel_w = (const float*)d_in[4];
    float* out = (float*)d_out;

    // ws layout: qkv bf16 [1024*1536*81] | wb bf16 [1536*512] | xT bf16 [1024*96*512]
    unsigned short* qkv = (unsigned short*)d_ws;
    unsigned short* wb  = qkv + (size_t)NB * O3 * NT;
    unsigned short* xT  = wb + (size_t)O3 * DM;
    size_t need = ((size_t)NB * O3 * NT + (size_t)O3 * DM + (size_t)NB * NP * DM) * 2;

    conv_w<<<dim3((O3 * DM + 255) / 256), dim3(256), 0, stream>>>(qkv_w, wb, O3 * DM);
    if (ws_size >= need) {
        transpose_x<<<dim3(NB * 8), dim3(256), 0, stream>>>(x, xT);
        qkv_gemm_a<<<dim3(NB * 6), dim3(256), 0, stream>>>(xT, wb, qkv_b, rel_h, rel_w, qkv);
    } else {
        qkv_gemm_fb<<<dim3(NB * 12), dim3(256), 0, stream>>>(x, wb, qkv_b, rel_h, rel_w, qkv);
    }
    attn<<<dim3(NB * NH), dim3(384), 0, stream>>>(qkv, out);
}